// Round 4
// baseline (1221.707 us; speedup 1.0000x reference)
//
#include <hip/hip_runtime.h>

#define BT_ROWS 65536      // 8*8192 rows
#define DIM     512
#define NK      32
#define TPB     256
#define RPB     32                     // rows per block (4 waves x 8 rows)
#define NBLK    (BT_ROWS / RPB)        // 2048 blocks -> 8 blocks/CU queued, 4 waves/SIMD resident

typedef float f4 __attribute__((ext_vector_type(4)));

// d_ws layout: float c2[NK] | float blockloss[NBLK] | int counts[NK]

__global__ void vq_prep(const float* __restrict__ cb, float* __restrict__ c2,
                        int* __restrict__ counts) {
    int t = threadIdx.x;
    if (t < NK) {
        const f4* c4 = (const f4*)(cb + t * DIM);
        float s = 0.f;
#pragma unroll 8
        for (int i = 0; i < DIM / 4; ++i) {
            f4 v = c4[i];
            s += v.x * v.x + v.y * v.y + v.z * v.z + v.w * v.w;
        }
        c2[t] = s;
    } else if (t < 2 * NK) {
        counts[t - NK] = 0;
    }
}

// Lane layout: lane = r*8 + part.  Row r of the wave is handled by 8 lanes;
// lane owns the f4 elements {part + 8t, t=0..15} of its row, so every global
// load instruction covers contiguous 128B runs (8 runs for x, 1 run for cb).
__global__ __launch_bounds__(TPB, 4) void vq_main(const float* __restrict__ x,
                                                  const float* __restrict__ cb,
                                                  const float* __restrict__ c2,
                                                  float* __restrict__ out,
                                                  float* __restrict__ blockloss,
                                                  int* __restrict__ counts) {
    const int tid  = threadIdx.x;
    const int lane = tid & 63;
    const int wv   = tid >> 6;        // wave 0..3
    const int part = lane & 7;        // f4 interleave position 0..7
    const int r    = lane >> 3;       // row-in-wave 0..7
    const int row  = blockIdx.x * RPB + wv * 8 + r;

    __shared__ float         wls[TPB / 64];
    __shared__ int           hist[NK];
    __shared__ unsigned char karr[RPB];
    if (tid < NK) hist[tid] = 0;

    float acc[NK];
#pragma unroll
    for (int k = 0; k < NK; ++k) acc[k] = 0.f;
    float x2 = 0.f;

    const f4* __restrict__ xr  = (const f4*)(x + (size_t)row * DIM);
    const f4* __restrict__ cb4 = (const f4*)cb;

#pragma unroll
    for (int half = 0; half < 2; ++half) {
        f4 xv[8];
#pragma unroll
        for (int t = 0; t < 8; ++t) xv[t] = xr[part + 8 * (half * 8 + t)];

#pragma unroll
        for (int t = 0; t < 8; ++t)
            x2 += xv[t].x * xv[t].x + xv[t].y * xv[t].y + xv[t].z * xv[t].z + xv[t].w * xv[t].w;

#pragma unroll
        for (int k = 0; k < NK; ++k) {
            const f4* cp = cb4 + k * (DIM / 4) + part;
            float s0 = 0.f, s1 = 0.f, s2 = 0.f, s3 = 0.f;
#pragma unroll
            for (int t = 0; t < 8; ++t) {
                f4 cv = cp[8 * (half * 8 + t)];   // one 128B contiguous run per wave instr
                s0 += xv[t].x * cv.x;
                s1 += xv[t].y * cv.y;
                s2 += xv[t].z * cv.z;
                s3 += xv[t].w * cv.w;
            }
            acc[k] += (s0 + s1) + (s2 + s3);
        }
    }

    // combine the 8 part-partials (lanes differing in bits 0..2 -> cheap DPP xors)
#pragma unroll
    for (int k = 0; k < NK; ++k) {
        acc[k] += __shfl_xor(acc[k], 1, 64);
        acc[k] += __shfl_xor(acc[k], 2, 64);
        acc[k] += __shfl_xor(acc[k], 4, 64);
    }
    x2 += __shfl_xor(x2, 1, 64);
    x2 += __shfl_xor(x2, 2, 64);
    x2 += __shfl_xor(x2, 4, 64);

    // dist_k = (x2 + c2[k]) - 2*acc[k]; keep-first ties (ascending k) like np.argmin
    int   kmin = 0;
    float best = x2 + c2[0] - 2.f * acc[0];
#pragma unroll
    for (int k = 1; k < NK; ++k) {
        float d = x2 + c2[k] - 2.f * acc[k];
        if (d < best) { best = d; kmin = k; }
    }

    // best == ||q - x||^2 for this row; count each row once (part==0 lane)
    float ls = (part == 0) ? best : 0.f;
#pragma unroll
    for (int m = 32; m; m >>= 1) ls += __shfl_xor(ls, m, 64);
    if (lane == 0) wls[wv] = ls;

    __syncthreads();   // hist init visible before atomics
    if (part == 0) {
        karr[wv * 8 + r] = (unsigned char)kmin;
        atomicAdd(&hist[kmin], 1);
    }
    __syncthreads();   // karr/hist/wls complete

    if (tid == 0) blockloss[blockIdx.x] = wls[0] + wls[1] + wls[2] + wls[3];
    if (tid < NK) {
        int h = hist[tid];
        if (h) atomicAdd(&counts[tid], h);
    }

    // cooperative coalesced q-write: wave wv writes its 8 rows, 1KB per store pass
    f4* __restrict__ o4 = (f4*)out;
    const size_t wrow0 = (size_t)blockIdx.x * RPB + (size_t)(wv << 3);
#pragma unroll 1
    for (int rr = 0; rr < 8; ++rr) {
        int    kr   = karr[(wv << 3) + rr];           // LDS broadcast, uniform per wave
        size_t base = (wrow0 + (size_t)rr) * (DIM / 4);
        o4[base + lane]      = cb4[kr * (DIM / 4) + lane];
        o4[base + 64 + lane] = cb4[kr * (DIM / 4) + 64 + lane];
    }
}

__global__ void vq_final(const float* __restrict__ blockloss, const int* __restrict__ counts,
                         float* __restrict__ out) {
    int   t = threadIdx.x;      // 256 threads, NBLK = 2048
    float v = 0.f;
#pragma unroll
    for (int i = 0; i < NBLK / 256; ++i) v += blockloss[t + i * 256];
#pragma unroll
    for (int m = 32; m; m >>= 1) v += __shfl_xor(v, m, 64);
    __shared__ float red[4];
    if ((t & 63) == 0) red[t >> 6] = v;
    __syncthreads();
    if (t == 0)
        out[(size_t)BT_ROWS * DIM] =
            1.25f * (red[0] + red[1] + red[2] + red[3]) / (float)((size_t)BT_ROWS * DIM);
    if (t < NK)
        out[(size_t)BT_ROWS * DIM + 1 + t] = (float)counts[t];
}

extern "C" void kernel_launch(void* const* d_in, const int* in_sizes, int n_in,
                              void* d_out, int out_size, void* d_ws, size_t ws_size,
                              hipStream_t stream) {
    const float* x  = (const float*)d_in[0];
    const float* cb = (const float*)d_in[1];
    float* out = (float*)d_out;

    float* c2        = (float*)d_ws;
    float* blockloss = c2 + NK;
    int*   counts    = (int*)(blockloss + NBLK);

    vq_prep<<<1, 64, 0, stream>>>(cb, c2, counts);
    vq_main<<<NBLK, TPB, 0, stream>>>(x, cb, c2, out, blockloss, counts);
    vq_final<<<1, 256, 0, stream>>>(blockloss, counts, out);
}

// Round 5
// 237.453 us; speedup vs baseline: 5.1451x; 5.1451x over previous
//
#include <hip/hip_runtime.h>

#define BT_ROWS 65536      // 8*8192 rows
#define DIM     512
#define NK      32
#define TPB     1024                   // 16 waves: 4 k-groups x 256 rows
#define RPB     256                    // rows per block
#define NBLK    (BT_ROWS / RPB)        // 256 blocks = 1 per CU, 4 waves/SIMD
#define KG      4                      // k-groups
#define KPG     (NK / KG)              // 8 codebooks per thread

typedef float f4 __attribute__((ext_vector_type(4)));

// d_ws layout: float c2[NK] | float blockloss[NBLK] | int counts[NK]

__global__ void vq_prep(const float* __restrict__ cb, float* __restrict__ c2,
                        int* __restrict__ counts) {
    int t = threadIdx.x;
    if (t < NK) {
        const f4* c4 = (const f4*)(cb + t * DIM);
        float s = 0.f;
#pragma unroll 8
        for (int i = 0; i < DIM / 4; ++i) {
            f4 v = c4[i];
            s += v.x * v.x + v.y * v.y + v.z * v.z + v.w * v.w;
        }
        c2[t] = s;
    } else if (t < 2 * NK) {
        counts[t - NK] = 0;
    }
}

__global__ __launch_bounds__(TPB, 4) void vq_main(const float* __restrict__ x,
                                                  const float* __restrict__ cb,
                                                  const float* __restrict__ c2,
                                                  float* __restrict__ out,
                                                  float* __restrict__ blockloss,
                                                  int* __restrict__ counts) {
    const int tid  = threadIdx.x;
    const int rid  = tid & 255;       // row within block
    const int kg   = tid >> 8;        // k-group 0..3 (wave-uniform)
    const int lane = tid & 63;
    const int wv   = tid >> 6;        // wave 0..15
    const int row  = blockIdx.x * RPB + rid;

    __shared__ float         bestd[KG * RPB];   // [kg][rid]
    __shared__ unsigned char bestk[KG * RPB];
    __shared__ float         wls[4];
    __shared__ int           hist[NK];
    __shared__ unsigned char karr[RPB];
    if (tid < NK) hist[tid] = 0;

    float acc[KPG];
#pragma unroll
    for (int k = 0; k < KPG; ++k) acc[k] = 0.f;
    float x2 = 0.f;

    const f4* __restrict__ xr  = (const f4*)(x + (size_t)row * DIM);
    const f4* __restrict__ cb4 = (const f4*)cb + (size_t)(kg * KPG) * (DIM / 4);

    // R1-proven pattern: each lane streams its own row, 32 floats per chunk
#pragma unroll 2
    for (int c = 0; c < DIM / 32; ++c) {
        f4 xv[8];
#pragma unroll
        for (int j = 0; j < 8; ++j) xv[j] = xr[c * 8 + j];

#pragma unroll
        for (int j = 0; j < 8; ++j)
            x2 += xv[j].x * xv[j].x + xv[j].y * xv[j].y + xv[j].z * xv[j].z + xv[j].w * xv[j].w;

#pragma unroll
        for (int k = 0; k < KPG; ++k) {
            const f4* cp = cb4 + k * (DIM / 4) + c * 8;   // wave-uniform address
            float s0 = 0.f, s1 = 0.f, s2 = 0.f, s3 = 0.f;
#pragma unroll
            for (int j = 0; j < 8; ++j) {
                f4 cv = cp[j];
                s0 += xv[j].x * cv.x;
                s1 += xv[j].y * cv.y;
                s2 += xv[j].z * cv.z;
                s3 += xv[j].w * cv.w;
            }
            acc[k] += (s0 + s1) + (s2 + s3);
        }
    }

    // thread-local argmin over this k-group (ascending k, keep-first ties)
    int   kmin = kg * KPG;
    float best = x2 + c2[kg * KPG] - 2.f * acc[0];
#pragma unroll
    for (int k = 1; k < KPG; ++k) {
        float d = x2 + c2[kg * KPG + k] - 2.f * acc[k];
        if (d < best) { best = d; kmin = kg * KPG + k; }
    }
    bestd[tid] = best;                 // tid == kg*256 + rid
    bestk[tid] = (unsigned char)kmin;
    __syncthreads();                   // also covers hist init

    if (kg == 0) {
        // combine the 4 k-group candidates in ascending-kg (== ascending-k) order
#pragma unroll
        for (int g = 1; g < KG; ++g) {
            float d = bestd[g * RPB + rid];
            if (d < best) { best = d; kmin = bestk[g * RPB + rid]; }
        }
        karr[rid] = (unsigned char)kmin;
        atomicAdd(&hist[kmin], 1);

        float ls = best;               // == ||q-x||^2 for this row
#pragma unroll
        for (int m = 32; m; m >>= 1) ls += __shfl_xor(ls, m, 64);
        if (lane == 0) wls[wv] = ls;
    }
    __syncthreads();

    if (tid == 0) blockloss[blockIdx.x] = wls[0] + wls[1] + wls[2] + wls[3];
    if (tid < NK) {
        int h = hist[tid];
        if (h) atomicAdd(&counts[tid], h);
    }

    // q-store: EXACT R1 shape (4 waves, 64 rows each, 1KB contiguous per instr)
    if (kg == 0) {
        const f4* __restrict__ cbw = (const f4*)cb;
        f4* __restrict__ o4 = (f4*)out;
        const size_t wrow0 = (size_t)blockIdx.x * RPB + (size_t)(wv << 6);
#pragma unroll 1
        for (int rr = 0; rr < 64; ++rr) {
            int    kr   = karr[(wv << 6) + rr];       // LDS broadcast, wave-uniform
            size_t base = (wrow0 + (size_t)rr) * (DIM / 4);
            o4[base + lane]      = cbw[kr * (DIM / 4) + lane];
            o4[base + 64 + lane] = cbw[kr * (DIM / 4) + 64 + lane];
        }
    }
}

__global__ void vq_final(const float* __restrict__ blockloss, const int* __restrict__ counts,
                         float* __restrict__ out) {
    int   t = threadIdx.x;      // 256 threads, NBLK = 256
    float v = blockloss[t];
#pragma unroll
    for (int m = 32; m; m >>= 1) v += __shfl_xor(v, m, 64);
    __shared__ float red[4];
    if ((t & 63) == 0) red[t >> 6] = v;
    __syncthreads();
    if (t == 0)
        out[(size_t)BT_ROWS * DIM] =
            1.25f * (red[0] + red[1] + red[2] + red[3]) / (float)((size_t)BT_ROWS * DIM);
    if (t < NK)
        out[(size_t)BT_ROWS * DIM + 1 + t] = (float)counts[t];
}

extern "C" void kernel_launch(void* const* d_in, const int* in_sizes, int n_in,
                              void* d_out, int out_size, void* d_ws, size_t ws_size,
                              hipStream_t stream) {
    const float* x  = (const float*)d_in[0];
    const float* cb = (const float*)d_in[1];
    float* out = (float*)d_out;

    float* c2        = (float*)d_ws;
    float* blockloss = c2 + NK;
    int*   counts    = (int*)(blockloss + NBLK);

    vq_prep<<<1, 64, 0, stream>>>(cb, c2, counts);
    vq_main<<<NBLK, TPB, 0, stream>>>(x, cb, c2, out, blockloss, counts);
    vq_final<<<1, 256, 0, stream>>>(blockloss, counts, out);
}

// Round 6
// 110.182 us; speedup vs baseline: 11.0881x; 2.1551x over previous
//
#include <hip/hip_runtime.h>

#define BT_ROWS 65536      // 8*8192 rows
#define DIM     512
#define NK      32
#define TPB     512                    // 8 waves
#define RPB     128                    // rows per block
#define NBLK    (BT_ROWS / RPB)        // 512 blocks = 2/CU, 4 waves/SIMD
#define KG      4                      // k-groups (tid>>7)
#define KPG     (NK / KG)              // 8 codebooks per thread
#define NCHUNK  16                     // 512 dims / 32 dims per chunk (128B/row)

typedef float f4 __attribute__((ext_vector_type(4)));
typedef const __attribute__((address_space(1))) void GAS;
typedef __attribute__((address_space(3))) void LAS;

// d_ws layout: float c2[NK] | float blockloss[NBLK] | int counts[NK]

__global__ void vq_prep(const float* __restrict__ cb, float* __restrict__ c2,
                        int* __restrict__ counts) {
    int t = threadIdx.x;
    if (t < NK) {
        const f4* c4 = (const f4*)(cb + t * DIM);
        float s = 0.f;
#pragma unroll 8
        for (int i = 0; i < DIM / 4; ++i) {
            f4 v = c4[i];
            s += v.x * v.x + v.y * v.y + v.z * v.z + v.w * v.w;
        }
        c2[t] = s;
    } else if (t < 2 * NK) {
        counts[t - NK] = 0;
    }
}

__global__ __launch_bounds__(TPB, 4) void vq_main(const float* __restrict__ x,
                                                  const float* __restrict__ cb,
                                                  const float* __restrict__ c2,
                                                  float* __restrict__ out,
                                                  float* __restrict__ blockloss,
                                                  int* __restrict__ counts) {
    const int tid  = threadIdx.x;
    const int lane = tid & 63;
    const int wv   = tid >> 6;                         // wave 0..7
    const int rid  = tid & 127;                        // row within block
    const int kg   = __builtin_amdgcn_readfirstlane(tid >> 7);  // 0..3, wave-uniform

    __shared__ float         xbuf[2][RPB][32];         // 2 x 16KB, linear layout
    __shared__ float         bestd[KG][RPB];
    __shared__ unsigned char bestk[KG][RPB];
    __shared__ float         wls[2];
    __shared__ int           hist[NK];
    __shared__ unsigned char karr[RPB];
    if (tid < NK) hist[tid] = 0;

    // --- staging geometry: wave wv stages rows [wv*16, wv*16+16) per chunk,
    // two global_load_lds_dwordx4 (1KB each). LDS dest LINEAR (wave base + lane*16);
    // the XOR swizzle is applied on the GLOBAL source address (rule #21):
    // LDS slot s of row r holds global element s ^ (r&7).
    const int rA = wv * 16 + (lane >> 3);              // rows for instr A
    const int rB = rA + 8;                             // rows for instr B
    const int jA = (lane & 7) ^ (rA & 7);
    const int jB = (lane & 7) ^ (rB & 7);
    const char* xblk = (const char*)x + (size_t)blockIdx.x * RPB * (DIM * 4);
    const char* gA0  = xblk + (size_t)rA * (DIM * 4) + jA * 16;
    const char* gB0  = xblk + (size_t)rB * (DIM * 4) + jB * 16;

#define STAGE(b, c) do {                                                              \
    __builtin_amdgcn_global_load_lds((GAS*)(gA0 + (c) * 128),                         \
                                     (LAS*)&xbuf[b][wv * 16][0], 16, 0, 0);           \
    __builtin_amdgcn_global_load_lds((GAS*)(gB0 + (c) * 128),                         \
                                     (LAS*)&xbuf[b][wv * 16 + 8][0], 16, 0, 0);       \
} while (0)

    float acc[KPG];
#pragma unroll
    for (int k = 0; k < KPG; ++k) acc[k] = 0.f;
    float x2 = 0.f;

    const f4* __restrict__ cbk = (const f4*)cb + (size_t)(kg * KPG) * (DIM / 4);
    const int rsw = rid & 7;

    STAGE(0, 0);
    asm volatile("s_waitcnt vmcnt(0)" ::: "memory");
    __syncthreads();

#pragma unroll 1
    for (int c = 0; c < NCHUNK; ++c) {
        const int cur = c & 1;
        if (c + 1 < NCHUNK) STAGE(cur ^ 1, c + 1);     // prefetch hides under compute

        const float* xr = &xbuf[cur][rid][0];
#pragma unroll
        for (int j = 0; j < 8; ++j) {
            f4 xv = *(const f4*)(xr + ((j ^ rsw) << 2));   // conflict-free ds_read_b128
            x2 += xv.x * xv.x + xv.y * xv.y + xv.z * xv.z + xv.w * xv.w;
#pragma unroll
            for (int k = 0; k < KPG; ++k) {
                f4 cv = cbk[k * (DIM / 4) + c * 8 + j];    // uniform addr -> scalar path
                acc[k] += xv.x * cv.x + xv.y * cv.y + xv.z * cv.z + xv.w * cv.w;
            }
        }
        asm volatile("s_waitcnt vmcnt(0)" ::: "memory");   // next-chunk staging done
        __syncthreads();
    }
#undef STAGE

    // thread-local argmin over this k-group (ascending k, keep-first ties)
    const int kb = kg * KPG;
    int   kmin = kb;
    float best = x2 + c2[kb] - 2.f * acc[0];
#pragma unroll
    for (int k = 1; k < KPG; ++k) {
        float d = x2 + c2[kb + k] - 2.f * acc[k];
        if (d < best) { best = d; kmin = kb + k; }
    }
    bestd[kg][rid] = best;
    bestk[kg][rid] = (unsigned char)kmin;
    __syncthreads();

    if (kg == 0) {   // waves 0-1: combine in ascending-k order
#pragma unroll
        for (int g = 1; g < KG; ++g) {
            float d = bestd[g][rid];
            if (d < best) { best = d; kmin = bestk[g][rid]; }
        }
        karr[rid] = (unsigned char)kmin;
        atomicAdd(&hist[kmin], 1);

        float ls = best;                 // == ||q-x||^2 for this row
#pragma unroll
        for (int m = 32; m; m >>= 1) ls += __shfl_xor(ls, m, 64);
        if (lane == 0) wls[wv] = ls;
    }
    __syncthreads();

    if (tid == 0) blockloss[blockIdx.x] = wls[0] + wls[1];
    if (tid < NK) {
        int h = hist[tid];
        if (h) atomicAdd(&counts[tid], h);
    }

    // q-store: proven shape — each wave 16 rows, 1KB contiguous per instruction
    const f4* __restrict__ cbw = (const f4*)cb;
    f4* __restrict__ o4 = (f4*)out;
    const size_t wrow0 = (size_t)blockIdx.x * RPB + (size_t)(wv * 16);
#pragma unroll 1
    for (int rr = 0; rr < 16; ++rr) {
        int    kr   = karr[wv * 16 + rr];              // LDS broadcast, wave-uniform
        size_t base = (wrow0 + (size_t)rr) * (DIM / 4);
        o4[base + lane]      = cbw[kr * (DIM / 4) + lane];
        o4[base + 64 + lane] = cbw[kr * (DIM / 4) + 64 + lane];
    }
}

__global__ void vq_final(const float* __restrict__ blockloss, const int* __restrict__ counts,
                         float* __restrict__ out) {
    int   t = threadIdx.x;      // 256 threads, NBLK = 512
    float v = blockloss[t] + blockloss[t + 256];
#pragma unroll
    for (int m = 32; m; m >>= 1) v += __shfl_xor(v, m, 64);
    __shared__ float red[4];
    if ((t & 63) == 0) red[t >> 6] = v;
    __syncthreads();
    if (t == 0)
        out[(size_t)BT_ROWS * DIM] =
            1.25f * (red[0] + red[1] + red[2] + red[3]) / (float)((size_t)BT_ROWS * DIM);
    if (t < NK)
        out[(size_t)BT_ROWS * DIM + 1 + t] = (float)counts[t];
}

extern "C" void kernel_launch(void* const* d_in, const int* in_sizes, int n_in,
                              void* d_out, int out_size, void* d_ws, size_t ws_size,
                              hipStream_t stream) {
    const float* x  = (const float*)d_in[0];
    const float* cb = (const float*)d_in[1];
    float* out = (float*)d_out;

    float* c2        = (float*)d_ws;
    float* blockloss = c2 + NK;
    int*   counts    = (int*)(blockloss + NBLK);

    vq_prep<<<1, 64, 0, stream>>>(cb, c2, counts);
    vq_main<<<NBLK, TPB, 0, stream>>>(x, cb, c2, out, blockloss, counts);
    vq_final<<<1, 256, 0, stream>>>(blockloss, counts, out);
}

// Round 7
// 70.592 us; speedup vs baseline: 17.3065x; 1.5608x over previous
//
#include <hip/hip_runtime.h>

#define BT_ROWS 65536
#define DIM     512
#define NK      32
#define TPB     128                    // 2 waves x 32 rows
#define RPB     64
#define NBLK    (BT_ROWS / RPB)        // 1024 blocks -> 4 blocks/CU
#define CHUNK   64                     // dims per chunk (256B/row)
#define NCHUNK  (DIM / CHUNK)          // 8

typedef float f4 __attribute__((ext_vector_type(4)));
typedef float f32x16 __attribute__((ext_vector_type(16)));
typedef short bf16x8 __attribute__((ext_vector_type(8)));
typedef unsigned int u32x4 __attribute__((ext_vector_type(4)));
typedef const __attribute__((address_space(1))) void GAS;
typedef __attribute__((address_space(3))) void LAS;

union Frag { u32x4 q; unsigned int w[4]; bf16x8 v; };

// d_ws layout: float c2[32] | float blockloss[1024] | int counts[32] | pad | u32 cbh[8192] @ byte 8192

__global__ void vq_prep(const float* __restrict__ cb, float* __restrict__ c2,
                        int* __restrict__ counts, unsigned int* __restrict__ cbh32) {
    int t = threadIdx.x;               // 256 threads
    const f4* c4 = (const f4*)cb;
    // cb -> bf16 (RNE via v_cvt_pk_bf16_f32): 16384 elems = 8192 u32 words
#pragma unroll
    for (int i = 0; i < 16; ++i) {
        f4 v = c4[t * 16 + i];
        unsigned int w0, w1;
        asm("v_cvt_pk_bf16_f32 %0, %1, %2" : "=v"(w0) : "v"(v.x), "v"(v.y));
        asm("v_cvt_pk_bf16_f32 %0, %1, %2" : "=v"(w1) : "v"(v.z), "v"(v.w));
        cbh32[t * 32 + 2 * i]     = w0;
        cbh32[t * 32 + 2 * i + 1] = w1;
    }
    if (t < NK) {
        float s = 0.f;
#pragma unroll 8
        for (int i = 0; i < DIM / 4; ++i) {
            f4 v = c4[t * (DIM / 4) + i];
            s += v.x * v.x + v.y * v.y + v.z * v.z + v.w * v.w;
        }
        c2[t] = s;
    } else if (t < 2 * NK) {
        counts[t - NK] = 0;
    }
}

__global__ __launch_bounds__(TPB, 4) void vq_main(const float* __restrict__ x,
                                                  const float* __restrict__ cb,
                                                  const float* __restrict__ c2,
                                                  const unsigned short* __restrict__ cbh,
                                                  float* __restrict__ out,
                                                  float* __restrict__ blockloss,
                                                  int* __restrict__ counts) {
    const int tid  = threadIdx.x;
    const int lane = tid & 63;
    const int wv   = tid >> 6;             // wave 0..1
    const int tb   = wv * 32;              // wave's row-tile base within block
    const int R0   = blockIdx.x * RPB;

    __shared__ float         xbuf[2][RPB][CHUNK];   // 2 x 16KB fp32
    __shared__ float         bestd[RPB];
    __shared__ float         x2row[RPB];
    __shared__ unsigned char karr[RPB];
    __shared__ int           hist[NK];
    if (tid < NK) hist[tid] = 0;

    // ---- staging: 8 instrs/wave/chunk, each 1KB = 4 rows x 256B, linear LDS dest.
    // LDS slot s (16B) of row r holds GLOBAL slot s ^ (r&15)  (source-side swizzle).
    const char* stsrc[8];
#pragma unroll
    for (int t = 0; t < 8; ++t) {
        int rl = wv * 32 + t * 4 + (lane >> 4);
        int g  = (lane & 15) ^ (rl & 15);
        stsrc[t] = (const char*)x + (size_t)(R0 + rl) * (DIM * 4) + g * 16;
    }
#define STAGE(b, c) do {                                                         \
    _Pragma("unroll")                                                            \
    for (int t = 0; t < 8; ++t)                                                  \
        __builtin_amdgcn_global_load_lds((GAS*)(stsrc[t] + (size_t)(c) * 256),   \
                                         (LAS*)&xbuf[b][wv * 32 + t * 4][0],     \
                                         16, 0, 0);                              \
} while (0)

    f32x16 acc;
#pragma unroll
    for (int r = 0; r < 16; ++r) acc[r] = 0.f;
    float x2acc = 0.f;

    const int m   = tb + (lane & 31);      // A row (within block)
    const int sw  = m & 15;
    const int n   = lane & 31;             // B concept column
    const int kh  = (lane >> 5) << 3;      // k-run offset within 16-k step
    const float c2v = c2[n];

    STAGE(0, 0);
    asm volatile("s_waitcnt vmcnt(0)" ::: "memory");
    __syncthreads();

#pragma unroll 1
    for (int c = 0; c < NCHUNK; ++c) {
        const int cur = c & 1;
        if (c + 1 < NCHUNK) STAGE(cur ^ 1, c + 1);

        const f4* xrow = (const f4*)&xbuf[cur][m][0];   // 16 slots of 16B
#pragma unroll
        for (int s = 0; s < 4; ++s) {                   // 4 MFMA k-steps of 16
            const int tg = s * 4 + ((lane >> 5) << 1);
            f4 a0 = xrow[tg ^ sw];
            f4 a1 = xrow[(tg + 1) ^ sw];
            x2acc += a0.x * a0.x + a0.y * a0.y + a0.z * a0.z + a0.w * a0.w
                   + a1.x * a1.x + a1.y * a1.y + a1.z * a1.z + a1.w * a1.w;

            Frag fa;
            asm("v_cvt_pk_bf16_f32 %0, %1, %2" : "=v"(fa.w[0]) : "v"(a0.x), "v"(a0.y));
            asm("v_cvt_pk_bf16_f32 %0, %1, %2" : "=v"(fa.w[1]) : "v"(a0.z), "v"(a0.w));
            asm("v_cvt_pk_bf16_f32 %0, %1, %2" : "=v"(fa.w[2]) : "v"(a1.x), "v"(a1.y));
            asm("v_cvt_pk_bf16_f32 %0, %1, %2" : "=v"(fa.w[3]) : "v"(a1.z), "v"(a1.w));

            Frag fb;                                     // B: concept n, 8 bf16 at k
            fb.q = *(const u32x4*)(cbh + (size_t)n * DIM + c * CHUNK + s * 16 + kh);

            acc = __builtin_amdgcn_mfma_f32_32x32x16_bf16(fa.v, fb.v, acc, 0, 0, 0);
        }
        asm volatile("s_waitcnt vmcnt(0)" ::: "memory");
        __syncthreads();
    }
#undef STAGE

    // x2: lanes l and l^32 hold the two k-halves of row (l&31)+tb
    {
        float o = __shfl_xor(x2acc, 32, 64);
        if (lane < 32) x2row[tb + lane] = x2acc + o;
    }

    // per-reg argmin over 32 concepts (butterfly within each 32-lane half;
    // keep-first ties == smaller concept index wins)
#pragma unroll
    for (int r = 0; r < 16; ++r) {
        float val = c2v - 2.f * acc[r];
        int   idx = n;
#pragma unroll
        for (int off = 1; off <= 16; off <<= 1) {
            float ov = __shfl_xor(val, off, 64);
            int   oi = __shfl_xor(idx, off, 64);
            if (ov < val || (ov == val && oi < idx)) { val = ov; idx = oi; }
        }
        const int mrow = tb + (r & 3) + 8 * (r >> 2) + ((lane >> 5) << 2);
        if ((lane & 31) == 0) { bestd[mrow] = val; karr[mrow] = (unsigned char)idx; }
    }
    __syncthreads();

    // loss + histogram (wave 0 handles all 64 rows)
    if (tid < RPB) {
        float ls = x2row[tid] + bestd[tid];             // == ||x-q||^2 (expansion form)
        atomicAdd(&hist[karr[tid]], 1);
#pragma unroll
        for (int mo = 32; mo; mo >>= 1) ls += __shfl_xor(ls, mo, 64);
        if (tid == 0) blockloss[blockIdx.x] = ls;
    }
    __syncthreads();
    if (tid < NK) {
        int h = hist[tid];
        if (h) atomicAdd(&counts[tid], h);
    }

    // q-store: each wave its 32 rows, 1KB contiguous per instruction (proven shape)
    const f4* __restrict__ cb4 = (const f4*)cb;
    f4* __restrict__ o4 = (f4*)out;
#pragma unroll 1
    for (int rr = 0; rr < 32; ++rr) {
        int    kr   = karr[tb + rr];                    // LDS broadcast, wave-uniform
        size_t base = (size_t)(R0 + tb + rr) * (DIM / 4);
        o4[base + lane]      = cb4[kr * (DIM / 4) + lane];
        o4[base + 64 + lane] = cb4[kr * (DIM / 4) + 64 + lane];
    }
}

__global__ void vq_final(const float* __restrict__ blockloss, const int* __restrict__ counts,
                         float* __restrict__ out) {
    int   t = threadIdx.x;      // 256 threads, NBLK = 1024
    float v = blockloss[t] + blockloss[t + 256] + blockloss[t + 512] + blockloss[t + 768];
#pragma unroll
    for (int m = 32; m; m >>= 1) v += __shfl_xor(v, m, 64);
    __shared__ float red[4];
    if ((t & 63) == 0) red[t >> 6] = v;
    __syncthreads();
    if (t == 0)
        out[(size_t)BT_ROWS * DIM] =
            1.25f * (red[0] + red[1] + red[2] + red[3]) / (float)((size_t)BT_ROWS * DIM);
    if (t < NK)
        out[(size_t)BT_ROWS * DIM + 1 + t] = (float)counts[t];
}

extern "C" void kernel_launch(void* const* d_in, const int* in_sizes, int n_in,
                              void* d_out, int out_size, void* d_ws, size_t ws_size,
                              hipStream_t stream) {
    const float* x  = (const float*)d_in[0];
    const float* cb = (const float*)d_in[1];
    float* out = (float*)d_out;

    float* f         = (float*)d_ws;
    float* c2        = f;
    float* blockloss = f + NK;
    int*   counts    = (int*)(f + NK + NBLK);
    unsigned int*   cbh32 = (unsigned int*)((char*)d_ws + 8192);
    unsigned short* cbh   = (unsigned short*)cbh32;

    vq_prep<<<1, 256, 0, stream>>>(cb, c2, counts, cbh32);
    vq_main<<<NBLK, TPB, 0, stream>>>(x, cb, c2, cbh, out, blockloss, counts);
    vq_final<<<1, 256, 0, stream>>>(blockloss, counts, out);
}